// Round 1
// baseline (1553.473 us; speedup 1.0000x reference)
//
#include <hip/hip_runtime.h>

#define S_ 128
#define N_ 384
#define CM 256
#define CH 32
#define CZ 128

// ---------------- Kernel 1: LayerNorm + dual projection -------------------
// grid = S*N blocks, 64 threads (1 wave). Stores A,B as [N][S][32].
__global__ __launch_bounds__(64) void k_ln_proj(
    const float* __restrict__ m, const float* __restrict__ mask,
    const float* __restrict__ gamma, const float* __restrict__ beta,
    const float* __restrict__ w1, const float* __restrict__ b1,
    const float* __restrict__ w2, const float* __restrict__ b2,
    float* __restrict__ Abuf, float* __restrict__ Bbuf)
{
    __shared__ float ln[CM];
    const int row = blockIdx.x;           // row = s*N + n
    const int t = threadIdx.x;
    float4 x = ((const float4*)(m + (size_t)row * CM))[t];
    float sum = x.x + x.y + x.z + x.w;
    float ssq = x.x*x.x + x.y*x.y + x.z*x.z + x.w*x.w;
    #pragma unroll
    for (int off = 32; off >= 1; off >>= 1) {
        sum += __shfl_xor(sum, off, 64);
        ssq += __shfl_xor(ssq, off, 64);
    }
    const float mean = sum * (1.0f/CM);
    const float var  = ssq * (1.0f/CM) - mean*mean;
    const float rstd = rsqrtf(var + 1e-5f);
    float4 g  = ((const float4*)gamma)[t];
    float4 be = ((const float4*)beta)[t];
    float4 l;
    l.x = (x.x - mean)*rstd*g.x + be.x;
    l.y = (x.y - mean)*rstd*g.y + be.y;
    l.z = (x.z - mean)*rstd*g.z + be.z;
    l.w = (x.w - mean)*rstd*g.w + be.w;
    ((float4*)ln)[t] = l;
    __syncthreads();

    const int c = t & 31, sel = t >> 5;
    const float* __restrict__ w = sel ? w2 : w1;
    float a0 = 0.f, a1 = 0.f, a2 = 0.f, a3 = 0.f;
    #pragma unroll 8
    for (int k = 0; k < CM; k += 4) {
        a0 += ln[k+0] * w[(k+0)*CH + c];
        a1 += ln[k+1] * w[(k+1)*CH + c];
        a2 += ln[k+2] * w[(k+2)*CH + c];
        a3 += ln[k+3] * w[(k+3)*CH + c];
    }
    float acc = (a0 + a1) + (a2 + a3) + (sel ? b2[c] : b1[c]);
    const float mv = mask[row];
    const int s = row / N_, n = row - s * N_;
    float* dst = sel ? Bbuf : Abuf;
    dst[((size_t)n * S_ + s) * CH + c] = acc * mv;
}

// ---------------- Kernel 2: reciprocal norm -------------------------------
__global__ __launch_bounds__(N_) void k_rnorm(const float* __restrict__ mask,
                                              float* __restrict__ RN)
{
    const int i = blockIdx.x, j = threadIdx.x;
    float acc = 0.f;
    #pragma unroll 8
    for (int s = 0; s < S_; ++s)
        acc += mask[s*N_ + i] * mask[s*N_ + j];
    RN[i*N_ + j] = 1.0f / (acc + 1e-3f);
}

// ---------------- Kernel 3: fused outer-product + w_out GEMM --------------
// One block per 4x4 (i,j) pair tile. 256 threads (4 waves, wave = local i).
// Stage 2: outer[p][c][d] = sum_s A[i][s][c]*B[j][s][d], 4x4x4 reg blocking.
// Stage 3: [16 x 1024] @ w_out[1024 x 128] streamed from L2.
__global__ __launch_bounds__(256) void k_outer(
    const float* __restrict__ Abuf, const float* __restrict__ Bbuf,
    const float* __restrict__ RN, const float* __restrict__ wout,
    const float* __restrict__ bout, float* __restrict__ out)
{
    __shared__ float smem[16 * 1024];          // 64 KB, reused across phases
    float* As = smem;                           // [4][32][36] (pad 36 vs bank conflicts)
    float* Bs = smem + 4608;
    const int t = threadIdx.x;
    const int i0 = blockIdx.x * 4, j0 = blockIdx.y * 4;
    const int wave = t >> 6, lane = t & 63;
    const int c0 = (lane >> 3) * 4, d0 = (lane & 7) * 4;

    float acc[4][4][4];
    #pragma unroll
    for (int j = 0; j < 4; ++j)
        #pragma unroll
        for (int u = 0; u < 4; ++u)
            #pragma unroll
            for (int v = 0; v < 4; ++v) acc[j][u][v] = 0.f;

    for (int ck = 0; ck < 4; ++ck) {           // s chunks of 32
        const int s0 = ck * 32;
        __syncthreads();
        #pragma unroll
        for (int r = 0; r < 4; ++r) {
            int fidx = r * 256 + t;
            int ii  = fidx >> 8;
            int rem = fidx & 255;
            int ss  = rem >> 3;
            int cc  = (rem & 7) * 4;
            *(float4*)&As[ii*1152 + ss*36 + cc] =
                *(const float4*)&Abuf[(((size_t)(i0+ii))*S_ + s0+ss)*CH + cc];
            *(float4*)&Bs[ii*1152 + ss*36 + cc] =
                *(const float4*)&Bbuf[(((size_t)(j0+ii))*S_ + s0+ss)*CH + cc];
        }
        __syncthreads();
        const float* Ai = As + wave * 1152;
        #pragma unroll 2
        for (int ss = 0; ss < 32; ++ss) {
            float a4[4];
            *(float4*)a4 = *(const float4*)&Ai[ss*36 + c0];
            #pragma unroll
            for (int j = 0; j < 4; ++j) {
                float b4[4];
                *(float4*)b4 = *(const float4*)&Bs[j*1152 + ss*36 + d0];
                #pragma unroll
                for (int u = 0; u < 4; ++u)
                    #pragma unroll
                    for (int v = 0; v < 4; ++v)
                        acc[j][u][v] += a4[u] * b4[v];
            }
        }
    }

    // write outer tiles to LDS: O[p][cd], p = wave*4 + j  (16 x 1024 fp32)
    __syncthreads();
    #pragma unroll
    for (int j = 0; j < 4; ++j)
        #pragma unroll
        for (int u = 0; u < 4; ++u)
            *(float4*)&smem[(wave*4 + j)*1024 + (c0+u)*32 + d0] = *(float4*)acc[j][u];
    __syncthreads();

    // stage 3: each thread: 2 pairs x 4 z outputs
    const int zq = t & 31, pp = t >> 5;        // pp in 0..7 -> pairs pp, pp+8
    float4 bz = ((const float4*)bout)[zq];
    float o0a[4] = {bz.x, bz.y, bz.z, bz.w};
    float o1a[4] = {bz.x, bz.y, bz.z, bz.w};
    const float* Orow0 = smem + pp * 1024;
    const float* Orow1 = smem + (pp + 8) * 1024;
    #pragma unroll 4
    for (int cd = 0; cd < 1024; ++cd) {
        float4 w4 = *(const float4*)&wout[cd*CZ + zq*4];
        float o0 = Orow0[cd], o1 = Orow1[cd];
        o0a[0] += o0*w4.x; o0a[1] += o0*w4.y; o0a[2] += o0*w4.z; o0a[3] += o0*w4.w;
        o1a[0] += o1*w4.x; o1a[1] += o1*w4.y; o1a[2] += o1*w4.z; o1a[3] += o1*w4.w;
    }
    {
        const int i = i0 + (pp >> 2), j = j0 + (pp & 3);
        const float r = RN[i*N_ + j];
        float4 o; o.x = o0a[0]*r; o.y = o0a[1]*r; o.z = o0a[2]*r; o.w = o0a[3]*r;
        *(float4*)&out[((size_t)(i*N_ + j))*CZ + zq*4] = o;
    }
    {
        const int i = i0 + 2 + (pp >> 2), j = j0 + (pp & 3);
        const float r = RN[i*N_ + j];
        float4 o; o.x = o1a[0]*r; o.y = o1a[1]*r; o.z = o1a[2]*r; o.w = o1a[3]*r;
        *(float4*)&out[((size_t)(i*N_ + j))*CZ + zq*4] = o;
    }
}

extern "C" void kernel_launch(void* const* d_in, const int* in_sizes, int n_in,
                              void* d_out, int out_size, void* d_ws, size_t ws_size,
                              hipStream_t stream)
{
    const float* m    = (const float*)d_in[0];
    const float* mask = (const float*)d_in[1];
    const float* gam  = (const float*)d_in[2];
    const float* bet  = (const float*)d_in[3];
    const float* w1   = (const float*)d_in[4];
    const float* b1   = (const float*)d_in[5];
    const float* w2   = (const float*)d_in[6];
    const float* b2   = (const float*)d_in[7];
    const float* wout = (const float*)d_in[8];
    const float* bout = (const float*)d_in[9];
    float* out = (float*)d_out;

    float* Abuf = (float*)d_ws;                       // [N][S][32]
    float* Bbuf = Abuf + (size_t)N_ * S_ * CH;        // [N][S][32]
    float* RN   = Bbuf + (size_t)N_ * S_ * CH;        // [N][N]

    k_ln_proj<<<S_ * N_, 64, 0, stream>>>(m, mask, gam, bet, w1, b1, w2, b2, Abuf, Bbuf);
    k_rnorm<<<N_, N_, 0, stream>>>(mask, RN);
    dim3 grid(N_ / 4, N_ / 4);
    k_outer<<<grid, 256, 0, stream>>>(Abuf, Bbuf, RN, wout, bout, out);
}

// Round 2
// 449.266 us; speedup vs baseline: 3.4578x; 3.4578x over previous
//
#include <hip/hip_runtime.h>
#include <hip/hip_bf16.h>

#define S_ 128
#define N_ 384
#define CM 256
#define CH 32
#define CZ 128

typedef __attribute__((ext_vector_type(8))) __bf16 bf16x8;
typedef __attribute__((ext_vector_type(4))) float f32x4;

// ---------------- Kernel 1: LayerNorm + dual projection -------------------
// grid = S*N blocks, 64 threads (1 wave). Stores A,B transposed bf16 [N][CH][S].
__global__ __launch_bounds__(64) void k_ln_proj(
    const float* __restrict__ m, const float* __restrict__ mask,
    const float* __restrict__ gamma, const float* __restrict__ beta,
    const float* __restrict__ w1, const float* __restrict__ b1,
    const float* __restrict__ w2, const float* __restrict__ b2,
    __hip_bfloat16* __restrict__ At, __hip_bfloat16* __restrict__ Bt)
{
    __shared__ float ln[CM];
    const int row = blockIdx.x;           // row = s*N + n
    const int t = threadIdx.x;
    float4 x = ((const float4*)(m + (size_t)row * CM))[t];
    float sum = x.x + x.y + x.z + x.w;
    float ssq = x.x*x.x + x.y*x.y + x.z*x.z + x.w*x.w;
    #pragma unroll
    for (int off = 32; off >= 1; off >>= 1) {
        sum += __shfl_xor(sum, off, 64);
        ssq += __shfl_xor(ssq, off, 64);
    }
    const float mean = sum * (1.0f/CM);
    const float var  = ssq * (1.0f/CM) - mean*mean;
    const float rstd = rsqrtf(var + 1e-5f);
    float4 g  = ((const float4*)gamma)[t];
    float4 be = ((const float4*)beta)[t];
    float4 l;
    l.x = (x.x - mean)*rstd*g.x + be.x;
    l.y = (x.y - mean)*rstd*g.y + be.y;
    l.z = (x.z - mean)*rstd*g.z + be.z;
    l.w = (x.w - mean)*rstd*g.w + be.w;
    ((float4*)ln)[t] = l;
    __syncthreads();

    const int c = t & 31, sel = t >> 5;
    const float* __restrict__ w = sel ? w2 : w1;
    float a0 = 0.f, a1 = 0.f, a2 = 0.f, a3 = 0.f;
    #pragma unroll 8
    for (int k = 0; k < CM; k += 4) {
        a0 += ln[k+0] * w[(k+0)*CH + c];
        a1 += ln[k+1] * w[(k+1)*CH + c];
        a2 += ln[k+2] * w[(k+2)*CH + c];
        a3 += ln[k+3] * w[(k+3)*CH + c];
    }
    float acc = (a0 + a1) + (a2 + a3) + (sel ? b2[c] : b1[c]);
    const float mv = mask[row];
    const int s = row / N_, n = row - s * N_;
    __hip_bfloat16* dst = sel ? Bt : At;
    dst[((size_t)n * CH + c) * S_ + s] = __float2bfloat16(acc * mv);
}

// ---------------- Kernel 2: reciprocal norm -------------------------------
__global__ __launch_bounds__(N_) void k_rnorm(const float* __restrict__ mask,
                                              float* __restrict__ RN)
{
    const int i = blockIdx.x, j = threadIdx.x;
    float acc = 0.f;
    #pragma unroll 8
    for (int s = 0; s < S_; ++s)
        acc += mask[s*N_ + i] * mask[s*N_ + j];
    RN[i*N_ + j] = 1.0f / (acc + 1e-3f);
}

// ---------------- Kernel 2b: transpose w_out to bf16 [z][cd] --------------
__global__ __launch_bounds__(256) void k_wt(const float* __restrict__ wout,
                                            __hip_bfloat16* __restrict__ woutT)
{
    const int z = blockIdx.x;
    for (int cd = threadIdx.x; cd < CH*CH; cd += 256)
        woutT[(size_t)z * (CH*CH) + cd] = __float2bfloat16(wout[(size_t)cd * CZ + z]);
}

// ---------------- Kernel 3: fused MFMA outer-product + w_out GEMM ---------
// One block per 8x4 (i,j) pair tile (32 pairs). 256 threads = 4 waves.
// Stage 2 (MFMA): C[(i,c),(j,d)] = sum_s At[i,c,s]*Bt[j,d,s]; M=256,N=128,K=128.
//   Wave w owns M rows [w*64, w*64+64): 4 M-tiles x 8 N-tiles x 4 k-steps.
// O staged in LDS as bf16 [32 pairs][1024 cd], row stride 1032 (+8 pad so
//   stage-3 ds_read_b128 at stride 2064B spreads banks 2-way = free).
// Stage 3 (MFMA): out[p,z] = sum_cd O[p,cd]*woutT[z,cd]; M=32,N=128,K=1024.
//   Wave w owns z cols [w*32, w*32+32): 2 M-tiles x 2 N-tiles x 32 k-steps.
#define OSTR 1032
__global__ __launch_bounds__(256, 2) void k_opm(
    const __hip_bfloat16* __restrict__ At, const __hip_bfloat16* __restrict__ Bt,
    const float* __restrict__ RN, const __hip_bfloat16* __restrict__ woutT,
    const float* __restrict__ bout, float* __restrict__ out)
{
    __shared__ __hip_bfloat16 O[32 * OSTR];   // 64.5 KB
    const int t = threadIdx.x;
    const int wave = t >> 6, lane = t & 63;
    const int l15 = lane & 15, quad = lane >> 4;
    const int i0 = blockIdx.x * 8, j0 = blockIdx.y * 4;

    // ---- stage 2 ----
    f32x4 acc[4][8];
    const f32x4 z4 = {0.f, 0.f, 0.f, 0.f};
    #pragma unroll
    for (int mt = 0; mt < 4; ++mt)
        #pragma unroll
        for (int nt = 0; nt < 8; ++nt) acc[mt][nt] = z4;

    const __hip_bfloat16* Ag[4];
    #pragma unroll
    for (int mt = 0; mt < 4; ++mt) {
        const int Mrow = wave*64 + mt*16 + l15;       // = i_l*32 + c
        Ag[mt] = At + ((size_t)(i0 + (Mrow >> 5)) * CH + (Mrow & 31)) * S_ + quad*8;
    }
    const __hip_bfloat16* Bg[8];
    #pragma unroll
    for (int nt = 0; nt < 8; ++nt) {
        const int Ncol = nt*16 + l15;                 // = j_l*32 + d
        Bg[nt] = Bt + ((size_t)(j0 + (Ncol >> 5)) * CH + (Ncol & 31)) * S_ + quad*8;
    }

    #pragma unroll
    for (int kk = 0; kk < 4; ++kk) {
        bf16x8 af[4], bfr[8];
        #pragma unroll
        for (int mt = 0; mt < 4; ++mt)
            af[mt] = *(const bf16x8*)(Ag[mt] + kk*32);
        #pragma unroll
        for (int nt = 0; nt < 8; ++nt)
            bfr[nt] = *(const bf16x8*)(Bg[nt] + kk*32);
        #pragma unroll
        for (int mt = 0; mt < 4; ++mt)
            #pragma unroll
            for (int nt = 0; nt < 8; ++nt)
                acc[mt][nt] = __builtin_amdgcn_mfma_f32_16x16x32_bf16(
                    af[mt], bfr[nt], acc[mt][nt], 0, 0, 0);
    }

    // ---- write outer tiles to LDS: O[p][cd], p=i_l*4+j_l, cd=c*32+d ----
    #pragma unroll
    for (int mt = 0; mt < 4; ++mt) {
        const int mtile = wave*4 + mt;                // M-tile index 0..15
        const int i_l = mtile >> 1;
        const int cbase = (mtile & 1) * 16 + quad*4;  // c for reg r = cbase + r
        #pragma unroll
        for (int nt = 0; nt < 8; ++nt) {
            const int j_l = nt >> 1;
            const int d = (nt & 1) * 16 + l15;
            const int p = i_l*4 + j_l;
            #pragma unroll
            for (int r = 0; r < 4; ++r)
                O[p*OSTR + (cbase + r)*32 + d] = __float2bfloat16(acc[mt][nt][r]);
        }
    }
    __syncthreads();

    // ---- stage 3 ----
    f32x4 oacc[2][2];
    #pragma unroll
    for (int mt = 0; mt < 2; ++mt)
        #pragma unroll
        for (int nl = 0; nl < 2; ++nl) oacc[mt][nl] = z4;

    const __hip_bfloat16* Wg[2];
    #pragma unroll
    for (int nl = 0; nl < 2; ++nl) {
        const int zc = wave*32 + nl*16 + l15;
        Wg[nl] = woutT + (size_t)zc * (CH*CH) + quad*8;
    }

    #pragma unroll 4
    for (int kk = 0; kk < 32; ++kk) {
        bf16x8 a0 = *(const bf16x8*)&O[(l15     )*OSTR + kk*32 + quad*8];
        bf16x8 a1 = *(const bf16x8*)&O[(16 + l15)*OSTR + kk*32 + quad*8];
        bf16x8 b0 = *(const bf16x8*)(Wg[0] + kk*32);
        bf16x8 b1 = *(const bf16x8*)(Wg[1] + kk*32);
        oacc[0][0] = __builtin_amdgcn_mfma_f32_16x16x32_bf16(a0, b0, oacc[0][0], 0,0,0);
        oacc[0][1] = __builtin_amdgcn_mfma_f32_16x16x32_bf16(a0, b1, oacc[0][1], 0,0,0);
        oacc[1][0] = __builtin_amdgcn_mfma_f32_16x16x32_bf16(a1, b0, oacc[1][0], 0,0,0);
        oacc[1][1] = __builtin_amdgcn_mfma_f32_16x16x32_bf16(a1, b1, oacc[1][1], 0,0,0);
    }

    // ---- epilogue: out[(i*N+j)*CZ + z] = (D + bout[z]) * RN[i,j] ----
    #pragma unroll
    for (int nl = 0; nl < 2; ++nl) {
        const int zc = wave*32 + nl*16 + l15;
        const float bz = bout[zc];
        #pragma unroll
        for (int mt = 0; mt < 2; ++mt) {
            #pragma unroll
            for (int r = 0; r < 4; ++r) {
                const int p = mt*16 + quad*4 + r;
                const int i = i0 + (p >> 2), j = j0 + (p & 3);
                const float rn = RN[i*N_ + j];
                out[((size_t)(i*N_ + j))*CZ + zc] = (oacc[mt][nl][r] + bz) * rn;
            }
        }
    }
}

extern "C" void kernel_launch(void* const* d_in, const int* in_sizes, int n_in,
                              void* d_out, int out_size, void* d_ws, size_t ws_size,
                              hipStream_t stream)
{
    const float* m    = (const float*)d_in[0];
    const float* mask = (const float*)d_in[1];
    const float* gam  = (const float*)d_in[2];
    const float* bet  = (const float*)d_in[3];
    const float* w1   = (const float*)d_in[4];
    const float* b1   = (const float*)d_in[5];
    const float* w2   = (const float*)d_in[6];
    const float* b2   = (const float*)d_in[7];
    const float* wout = (const float*)d_in[8];
    const float* bout = (const float*)d_in[9];
    float* out = (float*)d_out;

    __hip_bfloat16* At    = (__hip_bfloat16*)d_ws;                 // [N][CH][S] bf16
    __hip_bfloat16* Bt    = At + (size_t)N_ * CH * S_;             // [N][CH][S] bf16
    __hip_bfloat16* woutT = Bt + (size_t)N_ * CH * S_;             // [CZ][1024] bf16
    float*          RN    = (float*)(woutT + (size_t)CZ * CH * CH);// [N][N] fp32

    k_ln_proj<<<S_ * N_, 64, 0, stream>>>(m, mask, gam, bet, w1, b1, w2, b2, At, Bt);
    k_rnorm<<<N_, N_, 0, stream>>>(mask, RN);
    k_wt<<<CZ, 256, 0, stream>>>(wout, woutT);
    dim3 grid(N_ / 8, N_ / 4);
    k_opm<<<grid, 256, 0, stream>>>(At, Bt, RN, woutT, bout, out);
}